// Round 1
// baseline (1245.200 us; speedup 1.0000x reference)
//
#include <hip/hip_runtime.h>

// P=4096, LMAX=64, D=512, H=512
typedef __attribute__((ext_vector_type(8))) short bf16x8;
typedef __attribute__((ext_vector_type(4))) float f32x4;

__device__ __forceinline__ ushort f2bf(float x) {
  unsigned u = __float_as_uint(x);
  unsigned r = (u + 0x7fffu + ((u >> 16) & 1u)) >> 16;
  return (ushort)r;
}

// ---------------- K0: weight transpose + bf16 convert ----------------
// in: [512 k][512 n] fp32  ->  out: [512 n][512 k] bf16
__global__ void transpose_convert(const float* __restrict__ w1, const float* __restrict__ w2,
                                  ushort* __restrict__ o1, ushort* __restrict__ o2) {
  __shared__ float tile[64][65];
  const float* src = (blockIdx.z == 0) ? w1 : w2;
  ushort* dst = (blockIdx.z == 0) ? o1 : o2;
  const int n0 = blockIdx.x * 64, k0 = blockIdx.y * 64;
  const int tx = threadIdx.x, ty = threadIdx.y;  // 64 x 4
#pragma unroll
  for (int i = 0; i < 16; ++i) {
    int k = ty + i * 4;
    tile[k][tx] = src[(size_t)(k0 + k) * 512 + n0 + tx];
  }
  __syncthreads();
#pragma unroll
  for (int i = 0; i < 16; ++i) {
    int n = ty + i * 4;
    dst[(size_t)(n0 + n) * 512 + k0 + tx] = f2bf(tile[tx][n]);
  }
}

// ---------------- K1: fused 64-row GEMM + score epilogue ----------------
// MODE 0: per-path node scores -> masked softmax over 64 -> weights out[p*64+l]
// MODE 1: path-level scores    -> raw score out[row]
template <int MODE>
__launch_bounds__(256, 2)
__global__ void score_gemm(const float* __restrict__ A,     // [grid*64, 512] fp32
                           const ushort* __restrict__ Bt,   // [512 n][512 k] bf16
                           const float* __restrict__ bias,  // [512]
                           const float* __restrict__ wout,  // [512]
                           const int* __restrict__ lengths, // MODE 0 only
                           float* __restrict__ out) {
  __shared__ ushort At[64 * 136];   // [64 m][128 k] padded +8 to break bank conflicts
  __shared__ float sred[4][64];
  const int tid = threadIdx.x;
  const int wv = tid >> 6;
  const int lane = tid & 63;
  const int ln = lane & 15;
  const int quad = lane >> 4;
  const int nb = wv * 128;
  const float* Ab = A + (size_t)blockIdx.x * 64 * 512;

  // preload bias / output weights / B row pointers for this wave's 8 n-subtiles
  float bv[8], wvv[8];
  const ushort* bp[8];
#pragma unroll
  for (int ns = 0; ns < 8; ++ns) {
    int n = nb + ns * 16 + ln;
    bv[ns] = bias[n];
    wvv[ns] = wout[n];
    bp[ns] = Bt + (size_t)n * 512 + quad * 8;
  }

  f32x4 acc[4][8];
  const f32x4 zero = {0.f, 0.f, 0.f, 0.f};
#pragma unroll
  for (int i = 0; i < 4; ++i)
#pragma unroll
    for (int j = 0; j < 8; ++j) acc[i][j] = zero;

  int aoff[4];
#pragma unroll
  for (int ms = 0; ms < 4; ++ms) aoff[ms] = (ms * 16 + ln) * 136 + quad * 8;

  for (int kc = 0; kc < 4; ++kc) {
    __syncthreads();
    // stage 64 x 128 chunk of A: fp32 global -> bf16 LDS
#pragma unroll
    for (int i = 0; i < 8; ++i) {
      int flat = i * 1024 + tid * 4;
      int row = flat >> 7;
      int col = flat & 127;
      float4 v = *(const float4*)(Ab + (size_t)row * 512 + kc * 128 + col);
      ushort4 u;
      u.x = f2bf(v.x); u.y = f2bf(v.y); u.z = f2bf(v.z); u.w = f2bf(v.w);
      *(ushort4*)(&At[row * 136 + col]) = u;
    }
    __syncthreads();
#pragma unroll
    for (int k0 = 0; k0 < 128; k0 += 32) {
      bf16x8 af[4];
#pragma unroll
      for (int ms = 0; ms < 4; ++ms)
        af[ms] = *(const bf16x8*)(&At[aoff[ms] + k0]);
#pragma unroll
      for (int ns = 0; ns < 8; ++ns) {
        bf16x8 bf = *(const bf16x8*)(bp[ns] + kc * 128 + k0);
#pragma unroll
        for (int ms = 0; ms < 4; ++ms)
          acc[ms][ns] = __builtin_amdgcn_mfma_f32_16x16x32_bf16(af[ms], bf, acc[ms][ns], 0, 0, 0);
      }
    }
  }

  // epilogue: s[m] += relu(h + bias) * wout, reduced over this wave's 128 n
  // C/D layout: col(n) = lane&15, row(m within 16) = quad*4 + reg
#pragma unroll
  for (int ms = 0; ms < 4; ++ms) {
#pragma unroll
    for (int r = 0; r < 4; ++r) {
      float s = 0.f;
#pragma unroll
      for (int ns = 0; ns < 8; ++ns) {
        float h = acc[ms][ns][r] + bv[ns];
        s += fmaxf(h, 0.f) * wvv[ns];
      }
      s += __shfl_xor(s, 1);
      s += __shfl_xor(s, 2);
      s += __shfl_xor(s, 4);
      s += __shfl_xor(s, 8);
      if (ln == 0) sred[wv][ms * 16 + quad * 4 + r] = s;
    }
  }
  __syncthreads();
  if (tid < 64) {
    float s = sred[0][tid] + sred[1][tid] + sred[2][tid] + sred[3][tid];
    if (MODE == 0) {
      const int len = lengths[blockIdx.x];
      const bool valid = tid < len;
      float sv = valid ? s : -1e30f;
      float mx = sv;
      mx = fmaxf(mx, __shfl_xor(mx, 1));
      mx = fmaxf(mx, __shfl_xor(mx, 2));
      mx = fmaxf(mx, __shfl_xor(mx, 4));
      mx = fmaxf(mx, __shfl_xor(mx, 8));
      mx = fmaxf(mx, __shfl_xor(mx, 16));
      mx = fmaxf(mx, __shfl_xor(mx, 32));
      float e = valid ? __expf(sv - mx) : 0.f;
      float tot = e;
      tot += __shfl_xor(tot, 1);
      tot += __shfl_xor(tot, 2);
      tot += __shfl_xor(tot, 4);
      tot += __shfl_xor(tot, 8);
      tot += __shfl_xor(tot, 16);
      tot += __shfl_xor(tot, 32);
      out[(size_t)blockIdx.x * 64 + tid] = e / tot;
    } else {
      out[(size_t)blockIdx.x * 64 + tid] = s;
    }
  }
}

// ---------------- K1b: paths_fea[p][d] = sum_l w[l] * X[p][l][d] ----------------
__global__ void wsum(const float* __restrict__ X, const float* __restrict__ wl,
                     float* __restrict__ fea) {
  __shared__ float w[64];
  const int p = blockIdx.x, tid = threadIdx.x;
  if (tid < 64) w[tid] = wl[(size_t)p * 64 + tid];
  __syncthreads();
  const float* Xp = X + (size_t)p * 32768;
  const int d0 = tid * 2;
  float ax = 0.f, ay = 0.f;
#pragma unroll
  for (int l = 0; l < 64; ++l) {
    float2 x = *(const float2*)(Xp + l * 512 + d0);
    ax = fmaf(w[l], x.x, ax);
    ay = fmaf(w[l], x.y, ay);
  }
  fea[(size_t)p * 512 + d0] = ax;
  fea[(size_t)p * 512 + d0 + 1] = ay;
}

// ---------------- K2b: softmax over 4096 path scores ----------------
__global__ void softmax_p(const float* __restrict__ a, float* __restrict__ aw) {
  const int tid = threadIdx.x;  // 256
  const int wv = tid >> 6;
  __shared__ float redm[4];
  __shared__ float reds[4];
  float v[16];
#pragma unroll
  for (int i = 0; i < 16; ++i) v[i] = a[i * 256 + tid];
  float mx = v[0];
#pragma unroll
  for (int i = 1; i < 16; ++i) mx = fmaxf(mx, v[i]);
  mx = fmaxf(mx, __shfl_xor(mx, 1));
  mx = fmaxf(mx, __shfl_xor(mx, 2));
  mx = fmaxf(mx, __shfl_xor(mx, 4));
  mx = fmaxf(mx, __shfl_xor(mx, 8));
  mx = fmaxf(mx, __shfl_xor(mx, 16));
  mx = fmaxf(mx, __shfl_xor(mx, 32));
  if ((tid & 63) == 0) redm[wv] = mx;
  __syncthreads();
  mx = fmaxf(fmaxf(redm[0], redm[1]), fmaxf(redm[2], redm[3]));
  float s = 0.f;
#pragma unroll
  for (int i = 0; i < 16; ++i) {
    v[i] = __expf(v[i] - mx);
    s += v[i];
  }
  s += __shfl_xor(s, 1);
  s += __shfl_xor(s, 2);
  s += __shfl_xor(s, 4);
  s += __shfl_xor(s, 8);
  s += __shfl_xor(s, 16);
  s += __shfl_xor(s, 32);
  if ((tid & 63) == 0) reds[wv] = s;
  __syncthreads();
  s = reds[0] + reds[1] + reds[2] + reds[3];
  const float inv = 1.f / s;
#pragma unroll
  for (int i = 0; i < 16; ++i) aw[i * 256 + tid] = v[i] * inv;
}

// ---------------- K2c: user_fea[d] += sum_p aw[p] * fea[p][d] ----------------
__global__ void user_accum(const float* __restrict__ fea, const float* __restrict__ aw,
                           float* __restrict__ out) {
  const int g = blockIdx.x, tid = threadIdx.x;
  const int d0 = tid * 2;
  float ax = 0.f, ay = 0.f;
  for (int p = g * 64; p < g * 64 + 64; ++p) {
    float w = aw[p];
    float2 x = *(const float2*)(fea + (size_t)p * 512 + d0);
    ax = fmaf(w, x.x, ax);
    ay = fmaf(w, x.y, ay);
  }
  atomicAdd(out + d0, ax);
  atomicAdd(out + d0 + 1, ay);
}

extern "C" void kernel_launch(void* const* d_in, const int* in_sizes, int n_in,
                              void* d_out, int out_size, void* d_ws, size_t ws_size,
                              hipStream_t stream) {
  const float* paths   = (const float*)d_in[0];
  const int*   lengths = (const int*)d_in[1];
  const float* pW1     = (const float*)d_in[2];
  const float* pb1     = (const float*)d_in[3];
  const float* pw2     = (const float*)d_in[4];
  // d_in[5] = pb2: constant shift inside softmax -> cancels, unused
  const float* aW1     = (const float*)d_in[6];
  const float* ab1     = (const float*)d_in[7];
  const float* aw2     = (const float*)d_in[8];
  // d_in[9] = ab2: cancels, unused
  float* out = (float*)d_out;

  char* ws = (char*)d_ws;
  ushort* W1T  = (ushort*)ws;                  // 512 KB
  ushort* aW1T = (ushort*)(ws + 524288);       // 512 KB
  float* wl    = (float*)(ws + 1048576);       // 1 MB   [4096][64]
  float* fea   = (float*)(ws + 2097152);       // 8 MB   [4096][512]
  float* avec  = (float*)(ws + 10485760);      // 16 KB  [4096]
  float* awp   = (float*)(ws + 10502144);      // 16 KB  [4096]

  hipMemsetAsync(d_out, 0, 512 * sizeof(float), stream);
  transpose_convert<<<dim3(8, 8, 2), dim3(64, 4), 0, stream>>>(pW1, aW1, W1T, aW1T);
  score_gemm<0><<<4096, 256, 0, stream>>>(paths, W1T, pb1, pw2, lengths, wl);
  wsum<<<4096, 256, 0, stream>>>(paths, wl, fea);
  score_gemm<1><<<64, 256, 0, stream>>>(fea, aW1T, ab1, aw2, nullptr, avec);
  softmax_p<<<1, 256, 0, stream>>>(avec, awp);
  user_accum<<<64, 256, 0, stream>>>(fea, awp, out);
}

// Round 2
// 991.339 us; speedup vs baseline: 1.2561x; 1.2561x over previous
//
#include <hip/hip_runtime.h>

// P=4096, LMAX=64, D=512, H=512
typedef __attribute__((ext_vector_type(8))) short bf16x8;
typedef __attribute__((ext_vector_type(8))) unsigned short u16x8;
typedef __attribute__((ext_vector_type(4))) float f32x4;

__device__ __forceinline__ ushort f2bf(float x) {
  unsigned u = __float_as_uint(x);
  unsigned r = (u + 0x7fffu + ((u >> 16) & 1u)) >> 16;
  return (ushort)r;
}

// ---------------- K0: weight transpose + bf16 convert ----------------
// in: [512 k][512 n] fp32  ->  out: [512 n][512 k] bf16
__global__ void transpose_convert(const float* __restrict__ w1, const float* __restrict__ w2,
                                  ushort* __restrict__ o1, ushort* __restrict__ o2) {
  __shared__ float tile[64][65];
  const float* src = (blockIdx.z == 0) ? w1 : w2;
  ushort* dst = (blockIdx.z == 0) ? o1 : o2;
  const int n0 = blockIdx.x * 64, k0 = blockIdx.y * 64;
  const int tx = threadIdx.x, ty = threadIdx.y;  // 64 x 4
#pragma unroll
  for (int i = 0; i < 16; ++i) {
    int k = ty + i * 4;
    tile[k][tx] = src[(size_t)(k0 + k) * 512 + n0 + tx];
  }
  __syncthreads();
#pragma unroll
  for (int i = 0; i < 16; ++i) {
    int n = ty + i * 4;
    dst[(size_t)(n0 + n) * 512 + k0 + tx] = f2bf(tile[tx][n]);
  }
}

// ---------------- K1: 128x128x(K=512) GEMM tile + fused score partial ----------------
// grid = (4 nblocks, M/128 mblocks); n-fastest so the 4 siblings sharing an
// A-tile are co-resident (L3 serves the re-reads).
// scores[m] += sum_n relu(A@B1 + b1)[m,n] * w2[n]   (atomic 4-way partial)
// LDS tiles are 16B-chunk XOR-swizzled: chunk c of row r stored at c^(r&7).
// This makes every ds_write_b128 / ds_read_b128 a perfectly even 8-words-per-bank
// access (conflict-free); unswizzled the MFMA-fragment reads are 16-way aliased.
__launch_bounds__(256, 3)
__global__ void gemm_score(const float* __restrict__ A,      // [M][512] fp32
                           const ushort* __restrict__ Bt,    // [512 n][512 k] bf16
                           const float* __restrict__ bias,   // [512]
                           const float* __restrict__ wout,   // [512]
                           float* __restrict__ scores) {     // [M], pre-zeroed
  __shared__ ushort As[128 * 64];
  __shared__ ushort Bs[128 * 64];
  __shared__ float sred[2][128];
  const int tid = threadIdx.x;
  const int wv = tid >> 6, lane = tid & 63;
  const int ln = lane & 15, quad = lane >> 4;
  const int wm = wv & 1, wn = wv >> 1;   // wave quadrant in the 128x128 tile
  const int m0 = blockIdx.y * 128;
  const int nb = blockIdx.x * 128;

  float bv[4], w2v[4];
#pragma unroll
  for (int ns = 0; ns < 4; ++ns) {
    int n = nb + wn * 64 + ns * 16 + ln;
    bv[ns] = bias[n];
    w2v[ns] = wout[n];
  }

  f32x4 acc[4][4];
  const f32x4 zero = {0.f, 0.f, 0.f, 0.f};
#pragma unroll
  for (int i = 0; i < 4; ++i)
#pragma unroll
    for (int j = 0; j < 4; ++j) acc[i][j] = zero;

  int arow[4], brow[4];
#pragma unroll
  for (int ms = 0; ms < 4; ++ms) arow[ms] = wm * 64 + ms * 16 + ln;
#pragma unroll
  for (int ns = 0; ns < 4; ++ns) brow[ns] = wn * 64 + ns * 16 + ln;

  for (int kc = 0; kc < 8; ++kc) {
    const int kb = kc * 64;
    __syncthreads();
    // stage A (fp32->bf16) and B (bf16) 128x64 tiles, swizzled
#pragma unroll
    for (int j = 0; j < 4; ++j) {
      int id = j * 256 + tid;
      int row = id >> 3, c = id & 7;
      int cs = (c ^ (row & 7)) * 8;
      const float* srcA = A + (size_t)(m0 + row) * 512 + kb + c * 8;
      float4 v0 = *(const float4*)srcA;
      float4 v1 = *(const float4*)(srcA + 4);
      u16x8 ua = {f2bf(v0.x), f2bf(v0.y), f2bf(v0.z), f2bf(v0.w),
                  f2bf(v1.x), f2bf(v1.y), f2bf(v1.z), f2bf(v1.w)};
      *(u16x8*)(&As[row * 64 + cs]) = ua;
      u16x8 ub = *(const u16x8*)(Bt + (size_t)(nb + row) * 512 + kb + c * 8);
      *(u16x8*)(&Bs[row * 64 + cs]) = ub;
    }
    __syncthreads();
#pragma unroll
    for (int k0 = 0; k0 < 2; ++k0) {
      bf16x8 af[4], bfr[4];
#pragma unroll
      for (int ms = 0; ms < 4; ++ms) {
        int r = arow[ms];
        af[ms] = *(const bf16x8*)(&As[r * 64 + (((quad + k0 * 4) ^ (r & 7)) * 8)]);
      }
#pragma unroll
      for (int ns = 0; ns < 4; ++ns) {
        int r = brow[ns];
        bfr[ns] = *(const bf16x8*)(&Bs[r * 64 + (((quad + k0 * 4) ^ (r & 7)) * 8)]);
      }
#pragma unroll
      for (int ms = 0; ms < 4; ++ms)
#pragma unroll
        for (int ns = 0; ns < 4; ++ns)
          acc[ms][ns] = __builtin_amdgcn_mfma_f32_16x16x32_bf16(af[ms], bfr[ns], acc[ms][ns], 0, 0, 0);
    }
  }

  // epilogue: partial score over this block's 128 n
  // C/D layout: n = ln, m = quad*4 + r (within 16x16 subtile)
#pragma unroll
  for (int ms = 0; ms < 4; ++ms) {
#pragma unroll
    for (int r = 0; r < 4; ++r) {
      float s = 0.f;
#pragma unroll
      for (int ns = 0; ns < 4; ++ns)
        s += fmaxf(acc[ms][ns][r] + bv[ns], 0.f) * w2v[ns];
      s += __shfl_xor(s, 1);
      s += __shfl_xor(s, 2);
      s += __shfl_xor(s, 4);
      s += __shfl_xor(s, 8);
      if (ln == 0) sred[wn][wm * 64 + ms * 16 + quad * 4 + r] = s;
    }
  }
  __syncthreads();
  if (tid < 128) atomicAdd(&scores[m0 + tid], sred[0][tid] + sred[1][tid]);
}

// ---------------- K2: masked softmax over 64 nodes per path (in-place) ----------------
__global__ void node_softmax(float* __restrict__ s_wl, const int* __restrict__ lengths) {
  const int p = blockIdx.x * 4 + (threadIdx.x >> 6);
  const int l = threadIdx.x & 63;
  float s = s_wl[(size_t)p * 64 + l];
  const int len = lengths[p];
  const bool valid = l < len;
  float sv = valid ? s : -1e30f;
  float mx = sv;
  mx = fmaxf(mx, __shfl_xor(mx, 1));
  mx = fmaxf(mx, __shfl_xor(mx, 2));
  mx = fmaxf(mx, __shfl_xor(mx, 4));
  mx = fmaxf(mx, __shfl_xor(mx, 8));
  mx = fmaxf(mx, __shfl_xor(mx, 16));
  mx = fmaxf(mx, __shfl_xor(mx, 32));
  float e = valid ? __expf(sv - mx) : 0.f;
  float tot = e;
  tot += __shfl_xor(tot, 1);
  tot += __shfl_xor(tot, 2);
  tot += __shfl_xor(tot, 4);
  tot += __shfl_xor(tot, 8);
  tot += __shfl_xor(tot, 16);
  tot += __shfl_xor(tot, 32);
  s_wl[(size_t)p * 64 + l] = e / tot;
}

// ---------------- K3: paths_fea[p][d] = sum_l w[l] * X[p][l][d] ----------------
__global__ void wsum(const float* __restrict__ X, const float* __restrict__ wl,
                     float* __restrict__ fea) {
  __shared__ float w[64];
  const int p = blockIdx.x, tid = threadIdx.x;  // 128 threads
  if (tid < 64) w[tid] = wl[(size_t)p * 64 + tid];
  __syncthreads();
  const float* Xp = X + (size_t)p * 32768;
  const int d0 = tid * 4;
  float4 a = {0.f, 0.f, 0.f, 0.f};
#pragma unroll
  for (int l = 0; l < 64; ++l) {
    float4 x = *(const float4*)(Xp + l * 512 + d0);
    a.x = fmaf(w[l], x.x, a.x);
    a.y = fmaf(w[l], x.y, a.y);
    a.z = fmaf(w[l], x.z, a.z);
    a.w = fmaf(w[l], x.w, a.w);
  }
  *(float4*)(fea + (size_t)p * 512 + d0) = a;
}

// ---------------- K4: softmax over 4096 path scores ----------------
__global__ void softmax_p(const float* __restrict__ a, float* __restrict__ aw) {
  const int tid = threadIdx.x;  // 256
  const int wv = tid >> 6;
  __shared__ float redm[4];
  __shared__ float reds[4];
  float v[16];
#pragma unroll
  for (int i = 0; i < 16; ++i) v[i] = a[i * 256 + tid];
  float mx = v[0];
#pragma unroll
  for (int i = 1; i < 16; ++i) mx = fmaxf(mx, v[i]);
  mx = fmaxf(mx, __shfl_xor(mx, 1));
  mx = fmaxf(mx, __shfl_xor(mx, 2));
  mx = fmaxf(mx, __shfl_xor(mx, 4));
  mx = fmaxf(mx, __shfl_xor(mx, 8));
  mx = fmaxf(mx, __shfl_xor(mx, 16));
  mx = fmaxf(mx, __shfl_xor(mx, 32));
  if ((tid & 63) == 0) redm[wv] = mx;
  __syncthreads();
  mx = fmaxf(fmaxf(redm[0], redm[1]), fmaxf(redm[2], redm[3]));
  float s = 0.f;
#pragma unroll
  for (int i = 0; i < 16; ++i) {
    v[i] = __expf(v[i] - mx);
    s += v[i];
  }
  s += __shfl_xor(s, 1);
  s += __shfl_xor(s, 2);
  s += __shfl_xor(s, 4);
  s += __shfl_xor(s, 8);
  s += __shfl_xor(s, 16);
  s += __shfl_xor(s, 32);
  if ((tid & 63) == 0) reds[wv] = s;
  __syncthreads();
  s = reds[0] + reds[1] + reds[2] + reds[3];
  const float inv = 1.f / s;
#pragma unroll
  for (int i = 0; i < 16; ++i) aw[i * 256 + tid] = v[i] * inv;
}

// ---------------- K5: user_fea[d] += sum_p aw[p] * fea[p][d] ----------------
__global__ void user_accum(const float* __restrict__ fea, const float* __restrict__ aw,
                           float* __restrict__ out) {
  const int g = blockIdx.x, tid = threadIdx.x;
  const int d0 = tid * 2;
  float ax = 0.f, ay = 0.f;
  for (int p = g * 64; p < g * 64 + 64; ++p) {
    float w = aw[p];
    float2 x = *(const float2*)(fea + (size_t)p * 512 + d0);
    ax = fmaf(w, x.x, ax);
    ay = fmaf(w, x.y, ay);
  }
  atomicAdd(out + d0, ax);
  atomicAdd(out + d0 + 1, ay);
}

extern "C" void kernel_launch(void* const* d_in, const int* in_sizes, int n_in,
                              void* d_out, int out_size, void* d_ws, size_t ws_size,
                              hipStream_t stream) {
  const float* paths   = (const float*)d_in[0];
  const int*   lengths = (const int*)d_in[1];
  const float* pW1     = (const float*)d_in[2];
  const float* pb1     = (const float*)d_in[3];
  const float* pw2     = (const float*)d_in[4];
  // d_in[5] = pb2: constant shift inside softmax -> cancels, unused
  const float* aW1     = (const float*)d_in[6];
  const float* ab1     = (const float*)d_in[7];
  const float* aw2     = (const float*)d_in[8];
  // d_in[9] = ab2: cancels, unused
  float* out = (float*)d_out;

  char* ws = (char*)d_ws;
  ushort* W1T  = (ushort*)ws;                   // 512 KB
  ushort* aW1T = (ushort*)(ws + 524288);        // 512 KB
  float* nsc   = (float*)(ws + 1048576);        // 1 MB [262144] node scores -> softmax in place -> wl
  float* fea   = (float*)(ws + 2097152);        // 8 MB [4096][512]
  float* psc   = (float*)(ws + 10485760);       // 16 KB [4096] path scores
  float* awp   = (float*)(ws + 10502144);       // 16 KB [4096]

  hipMemsetAsync(nsc, 0, 262144 * sizeof(float), stream);
  hipMemsetAsync(psc, 0, 4096 * sizeof(float), stream);
  hipMemsetAsync(d_out, 0, 512 * sizeof(float), stream);

  transpose_convert<<<dim3(8, 8, 2), dim3(64, 4), 0, stream>>>(pW1, aW1, W1T, aW1T);
  // node-level: M = 262144 rows of X
  gemm_score<<<dim3(4, 2048), 256, 0, stream>>>(paths, W1T, pb1, pw2, nsc);
  node_softmax<<<1024, 256, 0, stream>>>(nsc, lengths);
  wsum<<<4096, 128, 0, stream>>>(paths, nsc, fea);
  // path-level: M = 4096 rows of fea
  gemm_score<<<dim3(4, 32), 256, 0, stream>>>(fea, aW1T, ab1, aw2, psc);
  softmax_p<<<1, 256, 0, stream>>>(psc, awp);
  user_accum<<<64, 256, 0, stream>>>(fea, awp, out);
}